// Round 15
// baseline (847.105 us; speedup 1.0000x reference)
//
#include <hip/hip_runtime.h>
#include <math.h>

// Problem constants
#define B_    512
#define T_    256
#define DIN   64
#define DS    64
#define KK    128   // DIN + DS
#define NN    2048
#define DOUT  10

// Tiling: 256 WGs = NTILES(4) x BTILES(64), 512 thr (8 waves), 1 WG/CU.
#define NT      512
#define BT      8
#define NTILES  (NN / NT)      // 4
#define BTILES  (B_ / BT)      // 64
#define THREADS 512
#define NWG     (NTILES * BTILES)   // 256

// Workspace (float offsets): ps[2] | EtSw (f16 B-frags) | SdSw (f16 B-frags) | counters
#define PS1        ((size_t)BTILES * NTILES * BT * DS)   // 131072 floats (512 KB)
#define PS_TOT     (2 * PS1)
#define ETSW_OFF   PS_TOT
#define ETSW_F16   ((size_t)KK * NN)                     // 262144 f16 = 512 KB
#define SDSW_OFF   (ETSW_OFF + ETSW_F16 / 2)
#define SDSW_F16   ((size_t)NN * DS)                     // 131072 f16 = 256 KB
#define BAR_OFF    (SDSW_OFF + SDSW_F16 / 2)
#define BAR_UINTS  4096

typedef _Float16 half8 __attribute__((ext_vector_type(8)));
typedef float    f32x4 __attribute__((ext_vector_type(4)));

__global__ __launch_bounds__(256) void pre_kernel(const float* __restrict__ enc,
                                                  const float* __restrict__ sd,
                                                  float* __restrict__ ws,
                                                  float* __restrict__ out) {
    size_t i = (size_t)blockIdx.x * blockDim.x + threadIdx.x;
    size_t stride = (size_t)gridDim.x * blockDim.x;
    unsigned int* bar = (unsigned int*)(ws + BAR_OFF);
    for (size_t x = i; x < BAR_UINTS; x += stride) bar[x] = 0u;
    // EtSw: B-fragments, 8-wave ownership (R13-verified).
    _Float16* EtSw = (_Float16*)(ws + ETSW_OFF);
    for (size_t x = i; x < (size_t)KK * NN; x += stride) {
        const int j     = (int)(x & 7);
        const int lane  = (int)((x >> 3) & 63);
        const int ktile = (int)((x >> 9) & 3);
        const int ntile = (int)((x >> 11) & 3);
        const int w     = (int)((x >> 13) & 7);
        const int nt    = (int)(x >> 16);
        const int n = nt * 512 + w * 64 + ntile * 16 + (lane & 15);
        const int k = ktile * 32 + ((lane >> 4) << 3) + j;
        EtSw[x] = (_Float16)enc[(size_t)n * KK + k];
    }
    // SdSw: decode B-fragments (R13-verified).
    _Float16* SdSw = (_Float16*)(ws + SDSW_OFF);
    for (size_t x = i; x < (size_t)NN * DS; x += stride) {
        const int j     = (int)(x & 7);
        const int lane  = (int)((x >> 3) & 63);
        const int ktile = (int)((x >> 9) & 7);
        const int kh    = (int)((x >> 12) & 1);
        const int cg    = (int)((x >> 13) & 3);
        const int nt    = (int)(x >> 15);
        const int n = nt * 512 + kh * 256 + ktile * 32 + ((lane >> 4) << 3) + j;
        const int c = cg * 16 + (lane & 15);
        SdSw[x] = (_Float16)sd[(size_t)n * DS + c];
    }
    for (size_t x = i; x < (size_t)B_ * DOUT; x += stride) out[x] = 0.0f;
}

// R14 structure (register-resident weight fragments, 660 us) with compressed
// per-step choreography: per-wave poll (no tid0 broadcast), per-wave arrive
// (16 producer-wave bumps per column per step, wait cnt >= 16t), u_{t+1}
// staged by decode-idle lanes, 3 barriers/step instead of 5.
// Overwrite safety: a wave stores ps[(t)&1] only after cnt >= 16t, which
// implies every peer's step-(t-1) fan-in read of the same-parity buffer
// completed (read -> store -> bump is per-wave program order).
__global__ __launch_bounds__(THREADS, 2) void persist_kernel(
    const float* __restrict__ seq,          // [B][T][DIN]
    const _Float16* __restrict__ EtSw,      // encoder B-fragments
    const _Float16* __restrict__ SdSw,      // state-decoder B-fragments
    const float* __restrict__ bias,
    const float* __restrict__ gain,
    const float* __restrict__ dec,   // [NN][DOUT]
    float* __restrict__ ps,          // [2][BTILES][NTILES][BT][DS]
    unsigned int* __restrict__ bar,  // cnt[BTILES * 32]
    float* __restrict__ out)
{
    __shared__ _Float16 xh[16][136];  // x_aug f16 (A-operand), rows 8..15 zero
    __shared__ _Float16 Ash[16][520]; // activations f16 (A-operand for decode)
    __shared__ float Dp[4][8][17];    // decode kh-pair partials

    const int tid = threadIdx.x;
    const int nt = blockIdx.x & (NTILES - 1);
    const int bt = blockIdx.x >> 2;
    const int n0 = nt * NT;
    const int b0 = bt * BT;

    unsigned int* cnt = bar + (size_t)bt * 32;

    const int w = tid >> 6;            // wave 0..7
    const int l = tid & 63;
    const int rs = tid >> 6;           // fan-in row 0..7
    const int cs = tid & 63;           // fan-in col
    const int m16 = l & 15;            // fragment row/col index
    const int q8  = (l >> 4) << 3;     // fragment k sub-offset
    const int cg  = w & 3;             // decode col group
    const int kh  = w >> 2;            // decode neuron half

    const _Float16* EtW = EtSw + ((size_t)(nt * 8 + w) << 13);
    const _Float16* SdW = SdSw + ((size_t)((nt * 4 + cg) * 2 + kh) << 12);

    // ---- register-resident weight fragments (loaded once) ----
    half8 etf[4][4];   // [ntile][ktile]
    #pragma unroll
    for (int n4 = 0; n4 < 4; ++n4)
        #pragma unroll
        for (int kt = 0; kt < 4; ++kt)
            etf[n4][kt] = *(const half8*)&EtW[(n4 << 11) + (kt << 9) + (size_t)l * 8];
    half8 sdf[8];
    #pragma unroll
    for (int kt = 0; kt < 8; ++kt)
        sdf[kt] = *(const half8*)&SdW[(kt << 9) + (size_t)l * 8];

    // epilogue params
    float gv[4], bv[4];
    #pragma unroll
    for (int n4 = 0; n4 < 4; ++n4) {
        gv[n4] = gain[n0 + w * 64 + n4 * 16 + m16];
        bv[n4] = bias[n0 + w * 64 + n4 * 16 + m16];
    }

    // preamble: zero xh, then stage u_0
    {
        unsigned int* xz = (unsigned int*)&xh[0][0];
        for (int i2 = tid; i2 < 16 * 136 / 2; i2 += THREADS) xz[i2] = 0u;
    }
    __syncthreads();
    if (tid < 128) {
        const int r = tid >> 4, c = (tid & 15) << 2;
        const float4 uv = *(const float4*)&seq[((size_t)(b0 + r) * T_ + 0) * DIN + c];
        _Float16* p = &xh[r][c];
        p[0] = (_Float16)uv.x; p[1] = (_Float16)uv.y;
        p[2] = (_Float16)uv.z; p[3] = (_Float16)uv.w;
    }
    __syncthreads();

    for (int t = 0; t < T_; ++t) {
        // ---- encode phase A: k-tiles 0,1 (u_t staged last step; no barrier) ----
        f32x4 acc[4];
        #pragma unroll
        for (int n4 = 0; n4 < 4; ++n4) acc[n4] = (f32x4){0.f, 0.f, 0.f, 0.f};
        {
            const half8 af0 = *(const half8*)&xh[m16][q8];
            const half8 af1 = *(const half8*)&xh[m16][32 + q8];
            #pragma unroll
            for (int n4 = 0; n4 < 4; ++n4) {
                acc[n4] = __builtin_amdgcn_mfma_f32_16x16x32_f16(af0, etf[n4][0], acc[n4], 0, 0, 0);
                acc[n4] = __builtin_amdgcn_mfma_f32_16x16x32_f16(af1, etf[n4][1], acc[n4], 0, 0, 0);
            }
        }

        // ---- acquire state s(t-1): PER-WAVE poll + fan-in (wave rs -> row rs) ----
        if (t > 0) {
            while (__hip_atomic_load(cnt, __ATOMIC_RELAXED, __HIP_MEMORY_SCOPE_AGENT)
                   < 16u * (unsigned)t)
                __builtin_amdgcn_s_sleep(1);
            const float* pb = ps + (size_t)((t - 1) & 1) * PS1;
            float ssum = 0.f;
            #pragma unroll
            for (int p = 0; p < NTILES; ++p)
                ssum += __hip_atomic_load(
                    pb + (((size_t)bt * NTILES + p) * BT + rs) * DS + cs,
                    __ATOMIC_RELAXED, __HIP_MEMORY_SCOPE_AGENT);
            xh[rs][DIN + cs] = (_Float16)ssum;
        } else {
            xh[rs][DIN + cs] = (_Float16)0.f;
        }
        __syncthreads();   // B1: state half ready

        // ---- encode phase B: k-tiles 2,3 ----
        {
            const half8 af2 = *(const half8*)&xh[m16][64 + q8];
            const half8 af3 = *(const half8*)&xh[m16][96 + q8];
            #pragma unroll
            for (int n4 = 0; n4 < 4; ++n4) {
                acc[n4] = __builtin_amdgcn_mfma_f32_16x16x32_f16(af2, etf[n4][2], acc[n4], 0, 0, 0);
                acc[n4] = __builtin_amdgcn_mfma_f32_16x16x32_f16(af3, etf[n4][3], acc[n4], 0, 0, 0);
            }
        }

        // ---- epilogue: rows 0..7 live in lanes 0..31 (row=(l>>4)*4+reg) ----
        if (l < 32) {
            const int rq = (l >> 4) << 2;
            #pragma unroll
            for (int n4 = 0; n4 < 4; ++n4) {
                const int n = w * 64 + n4 * 16 + m16;
                Ash[rq + 0][n] = (_Float16)fabsf(gv[n4] * acc[n4][0] + bv[n4]);
                Ash[rq + 1][n] = (_Float16)fabsf(gv[n4] * acc[n4][1] + bv[n4]);
                Ash[rq + 2][n] = (_Float16)fabsf(gv[n4] * acc[n4][2] + bv[n4]);
                Ash[rq + 3][n] = (_Float16)fabsf(gv[n4] * acc[n4][3] + bv[n4]);
            }
        }
        __syncthreads();   // B2: activations ready

        if (t == T_ - 1) {
            // ---- final projection: out += A_tile @ dec_tile ----
            for (int idx = tid; idx < BT * DOUT; idx += THREADS) {
                const int r = idx / DOUT;
                const int d = idx % DOUT;
                float o = 0.f;
                #pragma unroll 8
                for (int n = 0; n < NT; ++n)
                    o += (float)Ash[r][n] * dec[(size_t)(n0 + n) * DOUT + d];
                atomicAdd(&out[(size_t)(b0 + r) * DOUT + d], o);
            }
            return;
        }

        // ---- decode + u_{t+1} staging ----
        {
            f32x4 d0 = (f32x4){0.f, 0.f, 0.f, 0.f};
            f32x4 d1 = (f32x4){0.f, 0.f, 0.f, 0.f};
            #pragma unroll
            for (int kt = 0; kt < 8; kt += 2) {
                const half8 a0 = *(const half8*)&Ash[m16][kh * 256 + kt * 32 + q8];
                d0 = __builtin_amdgcn_mfma_f32_16x16x32_f16(a0, sdf[kt], d0, 0, 0, 0);
                const half8 a1 = *(const half8*)&Ash[m16][kh * 256 + (kt + 1) * 32 + q8];
                d1 = __builtin_amdgcn_mfma_f32_16x16x32_f16(a1, sdf[kt + 1], d1, 0, 0, 0);
            }
            d0[0] += d1[0]; d0[1] += d1[1]; d0[2] += d1[2]; d0[3] += d1[3];

            if (kh == 1) {
                if (l < 32) {
                    // publish K-half-1 partials
                    const int rq = (l >> 4) << 2;
                    Dp[cg][rq + 0][m16] = d0[0];
                    Dp[cg][rq + 1][m16] = d0[1];
                    Dp[cg][rq + 2][m16] = d0[2];
                    Dp[cg][rq + 3][m16] = d0[3];
                } else {
                    // decode-idle lanes stage u_{t+1} (rows 0..7, k 0..63)
                    const int idx = ((w - 4) << 5) + (l - 32);   // 0..127
                    const int r = idx >> 4, c = (idx & 15) << 2;
                    const float4 uv =
                        *(const float4*)&seq[((size_t)(b0 + r) * T_ + (t + 1)) * DIN + c];
                    _Float16* p = &xh[r][c];
                    p[0] = (_Float16)uv.x; p[1] = (_Float16)uv.y;
                    p[2] = (_Float16)uv.z; p[3] = (_Float16)uv.w;
                }
            }
            __syncthreads();   // B3: Dp ready + u_{t+1} staged

            if (kh == 0) {
                if (l < 32) {
                    const int rq = (l >> 4) << 2;
                    float* pw = ps + (size_t)(t & 1) * PS1
                                   + (((size_t)bt * NTILES + nt) * BT) * DS + 16 * cg + m16;
                    #pragma unroll
                    for (int r = 0; r < 4; ++r) {
                        const float v = d0[r] + Dp[cg][rq + r][m16];
                        __hip_atomic_store(pw + (size_t)(rq + r) * DS, v,
                                           __ATOMIC_RELAXED, __HIP_MEMORY_SCOPE_AGENT);
                    }
                }
                // per-wave arrive: drain own sc1 stores, bump
                asm volatile("s_waitcnt vmcnt(0)" ::: "memory");
                if (l == 0)
                    __hip_atomic_fetch_add(cnt, 1u, __ATOMIC_RELAXED, __HIP_MEMORY_SCOPE_AGENT);
            }
        }
        // no loop-top barrier: encode-A of t+1 reads xh[0..63] (staged pre-B3)
    }
}

extern "C" void kernel_launch(void* const* d_in, const int* in_sizes, int n_in,
                              void* d_out, int out_size, void* d_ws, size_t ws_size,
                              hipStream_t stream) {
    const float* seq  = (const float*)d_in[0];
    const float* enc  = (const float*)d_in[1];
    const float* bias = (const float*)d_in[2];
    const float* gain = (const float*)d_in[3];
    const float* sd   = (const float*)d_in[4];
    const float* dec  = (const float*)d_in[5];
    float* out = (float*)d_out;
    float* ws  = (float*)d_ws;   // ps[2] | EtSw | SdSw | counters  (~1.8 MB)

    pre_kernel<<<dim3(1024), dim3(256), 0, stream>>>(enc, sd, ws, out);

    float* ps = ws;
    const _Float16* EtSw = (const _Float16*)(ws + ETSW_OFF);
    const _Float16* SdSw = (const _Float16*)(ws + SDSW_OFF);
    unsigned int* bar = (unsigned int*)(ws + BAR_OFF);

    persist_kernel<<<dim3(NWG), dim3(THREADS), 0, stream>>>(
        seq, EtSw, SdSw, bias, gain, dec, ps, bar, out);
}

// Round 16
// 695.777 us; speedup vs baseline: 1.2175x; 1.2175x over previous
//
#include <hip/hip_runtime.h>
#include <math.h>

// Problem constants
#define B_    512
#define T_    256
#define DIN   64
#define DS    64
#define KK    128   // DIN + DS
#define NN    2048
#define DOUT  10

// Tiling: 256 WGs = NTILES(4) x BTILES(64), 512 thr (8 waves), 1 WG/CU.
#define NT      512
#define BT      8
#define NTILES  (NN / NT)      // 4
#define BTILES  (B_ / BT)      // 64
#define THREADS 512
#define NWG     (NTILES * BTILES)   // 256

// Workspace (float offsets): ps[2] | EtSw (f16 B-frags) | SdSw (f16 B-frags) | counters
#define PS1        ((size_t)BTILES * NTILES * BT * DS)   // 131072 floats (512 KB)
#define PS_TOT     (2 * PS1)
#define ETSW_OFF   PS_TOT
#define ETSW_F16   ((size_t)KK * NN)                     // 262144 f16 = 512 KB
#define SDSW_OFF   (ETSW_OFF + ETSW_F16 / 2)
#define SDSW_F16   ((size_t)NN * DS)                     // 131072 f16 = 256 KB
#define BAR_OFF    (SDSW_OFF + SDSW_F16 / 2)
#define BAR_UINTS  4096

typedef _Float16 half8 __attribute__((ext_vector_type(8)));
typedef float    f32x4 __attribute__((ext_vector_type(4)));

__global__ __launch_bounds__(256) void pre_kernel(const float* __restrict__ enc,
                                                  const float* __restrict__ sd,
                                                  float* __restrict__ ws,
                                                  float* __restrict__ out) {
    size_t i = (size_t)blockIdx.x * blockDim.x + threadIdx.x;
    size_t stride = (size_t)gridDim.x * blockDim.x;
    unsigned int* bar = (unsigned int*)(ws + BAR_OFF);
    for (size_t x = i; x < BAR_UINTS; x += stride) bar[x] = 0u;
    // EtSw: B-fragments, 8-wave ownership (R13-verified).
    _Float16* EtSw = (_Float16*)(ws + ETSW_OFF);
    for (size_t x = i; x < (size_t)KK * NN; x += stride) {
        const int j     = (int)(x & 7);
        const int lane  = (int)((x >> 3) & 63);
        const int ktile = (int)((x >> 9) & 3);
        const int ntile = (int)((x >> 11) & 3);
        const int w     = (int)((x >> 13) & 7);
        const int nt    = (int)(x >> 16);
        const int n = nt * 512 + w * 64 + ntile * 16 + (lane & 15);
        const int k = ktile * 32 + ((lane >> 4) << 3) + j;
        EtSw[x] = (_Float16)enc[(size_t)n * KK + k];
    }
    // SdSw: decode B-fragments (R13-verified).
    _Float16* SdSw = (_Float16*)(ws + SDSW_OFF);
    for (size_t x = i; x < (size_t)NN * DS; x += stride) {
        const int j     = (int)(x & 7);
        const int lane  = (int)((x >> 3) & 63);
        const int ktile = (int)((x >> 9) & 7);
        const int kh    = (int)((x >> 12) & 1);
        const int cg    = (int)((x >> 13) & 3);
        const int nt    = (int)(x >> 15);
        const int n = nt * 512 + kh * 256 + ktile * 32 + ((lane >> 4) << 3) + j;
        const int c = cg * 16 + (lane & 15);
        SdSw[x] = (_Float16)sd[(size_t)n * DS + c];
    }
    for (size_t x = i; x < (size_t)B_ * DOUT; x += stride) out[x] = 0.0f;
}

// R14 core (register-resident weights, 660 us) with choreography fixes:
//  - poll: tid0 ONLY (256 pollers chip-wide; R15's 2048 per-wave pollers
//    starved the counter RMWs -> 41 ms straggler) + barrier broadcast.
//  - arrive: per-wave (4 kh=0 waves drain own stores and bump; poll target
//    16t) — R15-tested, deletes the WG-wide arrive barrier.
//  - u_{t+1} staged by decode-idle lanes inside the Dp barrier — deletes the
//    loop-top staging barrier.
//  => 4 barriers/step (R14 had 6). Overwrite safety: cnt>=16t implies all 4
//  peer WGs passed step-(t-1) B4 (WG barriers order fan-in before bump).
__global__ __launch_bounds__(THREADS, 2) void persist_kernel(
    const float* __restrict__ seq,          // [B][T][DIN]
    const _Float16* __restrict__ EtSw,      // encoder B-fragments
    const _Float16* __restrict__ SdSw,      // state-decoder B-fragments
    const float* __restrict__ bias,
    const float* __restrict__ gain,
    const float* __restrict__ dec,   // [NN][DOUT]
    float* __restrict__ ps,          // [2][BTILES][NTILES][BT][DS]
    unsigned int* __restrict__ bar,  // cnt[BTILES * 32]
    float* __restrict__ out)
{
    __shared__ _Float16 xh[16][136];  // x_aug f16 (A-operand), rows 8..15 zero
    __shared__ _Float16 Ash[16][520]; // activations f16 (A-operand for decode)
    __shared__ float Dp[4][8][17];    // decode kh-pair partials

    const int tid = threadIdx.x;
    const int nt = blockIdx.x & (NTILES - 1);
    const int bt = blockIdx.x >> 2;
    const int n0 = nt * NT;
    const int b0 = bt * BT;

    unsigned int* cnt = bar + (size_t)bt * 32;

    const int w = tid >> 6;            // wave 0..7
    const int l = tid & 63;
    const int rs = tid >> 6;           // fan-in row 0..7
    const int cs = tid & 63;           // fan-in col
    const int m16 = l & 15;            // fragment row/col index
    const int q8  = (l >> 4) << 3;     // fragment k sub-offset
    const int cg  = w & 3;             // decode col group
    const int kh  = w >> 2;            // decode neuron half

    const _Float16* EtW = EtSw + ((size_t)(nt * 8 + w) << 13);
    const _Float16* SdW = SdSw + ((size_t)((nt * 4 + cg) * 2 + kh) << 12);

    // ---- register-resident weight fragments (loaded once) ----
    half8 etf[4][4];   // [ntile][ktile]
    #pragma unroll
    for (int n4 = 0; n4 < 4; ++n4)
        #pragma unroll
        for (int kt = 0; kt < 4; ++kt)
            etf[n4][kt] = *(const half8*)&EtW[(n4 << 11) + (kt << 9) + (size_t)l * 8];
    half8 sdf[8];
    #pragma unroll
    for (int kt = 0; kt < 8; ++kt)
        sdf[kt] = *(const half8*)&SdW[(kt << 9) + (size_t)l * 8];

    // epilogue params
    float gv[4], bv[4];
    #pragma unroll
    for (int n4 = 0; n4 < 4; ++n4) {
        gv[n4] = gain[n0 + w * 64 + n4 * 16 + m16];
        bv[n4] = bias[n0 + w * 64 + n4 * 16 + m16];
    }

    // preamble: zero xh, then stage u_0
    {
        unsigned int* xz = (unsigned int*)&xh[0][0];
        for (int i2 = tid; i2 < 16 * 136 / 2; i2 += THREADS) xz[i2] = 0u;
    }
    __syncthreads();
    if (tid < 128) {
        const int r = tid >> 4, c = (tid & 15) << 2;
        const float4 uv = *(const float4*)&seq[((size_t)(b0 + r) * T_ + 0) * DIN + c];
        _Float16* p = &xh[r][c];
        p[0] = (_Float16)uv.x; p[1] = (_Float16)uv.y;
        p[2] = (_Float16)uv.z; p[3] = (_Float16)uv.w;
    }
    __syncthreads();

    for (int t = 0; t < T_; ++t) {
        // ---- encode phase A: k-tiles 0,1 (u_t staged last step; no barrier) ----
        f32x4 acc[4];
        #pragma unroll
        for (int n4 = 0; n4 < 4; ++n4) acc[n4] = (f32x4){0.f, 0.f, 0.f, 0.f};
        {
            const half8 af0 = *(const half8*)&xh[m16][q8];
            const half8 af1 = *(const half8*)&xh[m16][32 + q8];
            #pragma unroll
            for (int n4 = 0; n4 < 4; ++n4) {
                acc[n4] = __builtin_amdgcn_mfma_f32_16x16x32_f16(af0, etf[n4][0], acc[n4], 0, 0, 0);
                acc[n4] = __builtin_amdgcn_mfma_f32_16x16x32_f16(af1, etf[n4][1], acc[n4], 0, 0, 0);
            }
        }

        // ---- acquire state s(t-1): tid0 poll (busy spin) + broadcast + fan-in ----
        if (t > 0) {
            if (tid == 0) {
                while (__hip_atomic_load(cnt, __ATOMIC_RELAXED, __HIP_MEMORY_SCOPE_AGENT)
                       < 16u * (unsigned)t) { }
            }
            __syncthreads();   // B1: generation observed
            const float* pb = ps + (size_t)((t - 1) & 1) * PS1;
            float ssum = 0.f;
            #pragma unroll
            for (int p = 0; p < NTILES; ++p)
                ssum += __hip_atomic_load(
                    pb + (((size_t)bt * NTILES + p) * BT + rs) * DS + cs,
                    __ATOMIC_RELAXED, __HIP_MEMORY_SCOPE_AGENT);
            xh[rs][DIN + cs] = (_Float16)ssum;
        } else {
            xh[rs][DIN + cs] = (_Float16)0.f;
        }
        __syncthreads();   // B2: state half ready

        // ---- encode phase B: k-tiles 2,3 ----
        {
            const half8 af2 = *(const half8*)&xh[m16][64 + q8];
            const half8 af3 = *(const half8*)&xh[m16][96 + q8];
            #pragma unroll
            for (int n4 = 0; n4 < 4; ++n4) {
                acc[n4] = __builtin_amdgcn_mfma_f32_16x16x32_f16(af2, etf[n4][2], acc[n4], 0, 0, 0);
                acc[n4] = __builtin_amdgcn_mfma_f32_16x16x32_f16(af3, etf[n4][3], acc[n4], 0, 0, 0);
            }
        }

        // ---- epilogue: rows 0..7 live in lanes 0..31 (row=(l>>4)*4+reg) ----
        if (l < 32) {
            const int rq = (l >> 4) << 2;
            #pragma unroll
            for (int n4 = 0; n4 < 4; ++n4) {
                const int n = w * 64 + n4 * 16 + m16;
                Ash[rq + 0][n] = (_Float16)fabsf(gv[n4] * acc[n4][0] + bv[n4]);
                Ash[rq + 1][n] = (_Float16)fabsf(gv[n4] * acc[n4][1] + bv[n4]);
                Ash[rq + 2][n] = (_Float16)fabsf(gv[n4] * acc[n4][2] + bv[n4]);
                Ash[rq + 3][n] = (_Float16)fabsf(gv[n4] * acc[n4][3] + bv[n4]);
            }
        }
        __syncthreads();   // B3: activations ready

        if (t == T_ - 1) {
            // ---- final projection: out += A_tile @ dec_tile ----
            for (int idx = tid; idx < BT * DOUT; idx += THREADS) {
                const int r = idx / DOUT;
                const int d = idx % DOUT;
                float o = 0.f;
                #pragma unroll 8
                for (int n = 0; n < NT; ++n)
                    o += (float)Ash[r][n] * dec[(size_t)(n0 + n) * DOUT + d];
                atomicAdd(&out[(size_t)(b0 + r) * DOUT + d], o);
            }
            return;
        }

        // ---- decode + u_{t+1} staging ----
        {
            f32x4 d0 = (f32x4){0.f, 0.f, 0.f, 0.f};
            f32x4 d1 = (f32x4){0.f, 0.f, 0.f, 0.f};
            #pragma unroll
            for (int kt = 0; kt < 8; kt += 2) {
                const half8 a0 = *(const half8*)&Ash[m16][kh * 256 + kt * 32 + q8];
                d0 = __builtin_amdgcn_mfma_f32_16x16x32_f16(a0, sdf[kt], d0, 0, 0, 0);
                const half8 a1 = *(const half8*)&Ash[m16][kh * 256 + (kt + 1) * 32 + q8];
                d1 = __builtin_amdgcn_mfma_f32_16x16x32_f16(a1, sdf[kt + 1], d1, 0, 0, 0);
            }
            d0[0] += d1[0]; d0[1] += d1[1]; d0[2] += d1[2]; d0[3] += d1[3];

            if (kh == 1) {
                if (l < 32) {
                    // publish K-half-1 partials
                    const int rq = (l >> 4) << 2;
                    Dp[cg][rq + 0][m16] = d0[0];
                    Dp[cg][rq + 1][m16] = d0[1];
                    Dp[cg][rq + 2][m16] = d0[2];
                    Dp[cg][rq + 3][m16] = d0[3];
                } else {
                    // decode-idle lanes stage u_{t+1} (rows 0..7, k 0..63)
                    const int idx = ((w - 4) << 5) + (l - 32);   // 0..127
                    const int r = idx >> 4, c = (idx & 15) << 2;
                    const float4 uv =
                        *(const float4*)&seq[((size_t)(b0 + r) * T_ + (t + 1)) * DIN + c];
                    _Float16* p = &xh[r][c];
                    p[0] = (_Float16)uv.x; p[1] = (_Float16)uv.y;
                    p[2] = (_Float16)uv.z; p[3] = (_Float16)uv.w;
                }
            }
            __syncthreads();   // B4: Dp ready + u_{t+1} staged

            if (kh == 0) {
                if (l < 32) {
                    const int rq = (l >> 4) << 2;
                    float* pw = ps + (size_t)(t & 1) * PS1
                                   + (((size_t)bt * NTILES + nt) * BT) * DS + 16 * cg + m16;
                    #pragma unroll
                    for (int r = 0; r < 4; ++r) {
                        const float v = d0[r] + Dp[cg][rq + r][m16];
                        __hip_atomic_store(pw + (size_t)(rq + r) * DS, v,
                                           __ATOMIC_RELAXED, __HIP_MEMORY_SCOPE_AGENT);
                    }
                }
                // per-wave arrive: drain own sc1 stores, bump (R15-tested)
                asm volatile("s_waitcnt vmcnt(0)" ::: "memory");
                if (l == 0)
                    __hip_atomic_fetch_add(cnt, 1u, __ATOMIC_RELAXED, __HIP_MEMORY_SCOPE_AGENT);
            }
        }
        // no loop-top barrier: encode-A of t+1 reads xh[0..63] (staged pre-B4)
    }
}

extern "C" void kernel_launch(void* const* d_in, const int* in_sizes, int n_in,
                              void* d_out, int out_size, void* d_ws, size_t ws_size,
                              hipStream_t stream) {
    const float* seq  = (const float*)d_in[0];
    const float* enc  = (const float*)d_in[1];
    const float* bias = (const float*)d_in[2];
    const float* gain = (const float*)d_in[3];
    const float* sd   = (const float*)d_in[4];
    const float* dec  = (const float*)d_in[5];
    float* out = (float*)d_out;
    float* ws  = (float*)d_ws;   // ps[2] | EtSw | SdSw | counters  (~1.8 MB)

    pre_kernel<<<dim3(1024), dim3(256), 0, stream>>>(enc, sd, ws, out);

    float* ps = ws;
    const _Float16* EtSw = (const _Float16*)(ws + ETSW_OFF);
    const _Float16* SdSw = (const _Float16*)(ws + SDSW_OFF);
    unsigned int* bar = (unsigned int*)(ws + BAR_OFF);

    persist_kernel<<<dim3(NWG), dim3(THREADS), 0, stream>>>(
        seq, EtSw, SdSw, bias, gain, dec, ps, bar, out);
}

// Round 17
// 640.947 us; speedup vs baseline: 1.3216x; 1.0855x over previous
//
#include <hip/hip_runtime.h>
#include <math.h>

// Problem constants
#define B_    512
#define T_    256
#define DIN   64
#define DS    64
#define KK    128   // DIN + DS
#define NN    2048
#define DOUT  10

// Tiling: 256 WGs = NTILES(4) x BTILES(64), 512 thr (8 waves), 1 WG/CU.
#define NT      512
#define BT      8
#define NTILES  (NN / NT)      // 4
#define BTILES  (B_ / BT)      // 64
#define THREADS 512
#define NWG     (NTILES * BTILES)   // 256

// Workspace: psq (u64 tagged partials, double-buffered) | EtSw | SdSw
#define PSQ_ELEMS  ((size_t)BTILES * NTILES * BT * DS)  // 131072 u64 per buffer
#define PS_FLOATS  (4 * PSQ_ELEMS)                      // 2 buffers as float count
#define ETSW_OFF   PS_FLOATS
#define ETSW_F16   ((size_t)KK * NN)                    // 262144 f16 = 512 KB
#define SDSW_OFF   (ETSW_OFF + ETSW_F16 / 2)
#define SDSW_F16   ((size_t)NN * DS)                    // 131072 f16 = 256 KB

typedef _Float16 half8 __attribute__((ext_vector_type(8)));
typedef float    f32x4 __attribute__((ext_vector_type(4)));

__global__ __launch_bounds__(256) void pre_kernel(const float* __restrict__ enc,
                                                  const float* __restrict__ sd,
                                                  float* __restrict__ ws,
                                                  float* __restrict__ out) {
    size_t i = (size_t)blockIdx.x * blockDim.x + threadIdx.x;
    size_t stride = (size_t)gridDim.x * blockDim.x;
    // zero tagged-partial buffers (tag 0 never matches: consumer tags are >= 1)
    unsigned long long* psq = (unsigned long long*)ws;
    for (size_t x = i; x < 2 * PSQ_ELEMS; x += stride) psq[x] = 0ull;
    // EtSw: B-fragments, 8-wave ownership (R13-verified).
    _Float16* EtSw = (_Float16*)(ws + ETSW_OFF);
    for (size_t x = i; x < (size_t)KK * NN; x += stride) {
        const int j     = (int)(x & 7);
        const int lane  = (int)((x >> 3) & 63);
        const int ktile = (int)((x >> 9) & 3);
        const int ntile = (int)((x >> 11) & 3);
        const int w     = (int)((x >> 13) & 7);
        const int nt    = (int)(x >> 16);
        const int n = nt * 512 + w * 64 + ntile * 16 + (lane & 15);
        const int k = ktile * 32 + ((lane >> 4) << 3) + j;
        EtSw[x] = (_Float16)enc[(size_t)n * KK + k];
    }
    // SdSw: decode B-fragments (R13-verified).
    _Float16* SdSw = (_Float16*)(ws + SDSW_OFF);
    for (size_t x = i; x < (size_t)NN * DS; x += stride) {
        const int j     = (int)(x & 7);
        const int lane  = (int)((x >> 3) & 63);
        const int ktile = (int)((x >> 9) & 7);
        const int kh    = (int)((x >> 12) & 1);
        const int cg    = (int)((x >> 13) & 3);
        const int nt    = (int)(x >> 15);
        const int n = nt * 512 + kh * 256 + ktile * 32 + ((lane >> 4) << 3) + j;
        const int c = cg * 16 + (lane & 15);
        SdSw[x] = (_Float16)sd[(size_t)n * DS + c];
    }
    for (size_t x = i; x < (size_t)B_ * DOUT; x += stride) out[x] = 0.0f;
}

// R14 core (register-resident weights, best measured: 660 us) with ONE
// exchange change: the generation counter is DELETED. Each partial is an 8B
// packed (tag<<32 | f32) relaxed-agent store (single-copy atomic); consumers
// spin on their own 4 packed words until tag == t. This merges drain + bump +
// observe + fan-in into one one-way MALL visibility latency, removes 2
// barriers, and distributes polling (each address polled by exactly 4 lanes
// chip-wide — the opposite of R15's 2048-waves-on-64-lines pathology).
// Overwrite safety (same induction as R14): producer writes buf[t&1] only
// after observing all tags t in buf[(t-1)&1], which implies every peer
// finished its step-(t-1) read of buf[t&1] (read -> store is barrier-ordered).
__global__ __launch_bounds__(THREADS, 2) void persist_kernel(
    const float* __restrict__ seq,          // [B][T][DIN]
    const _Float16* __restrict__ EtSw,      // encoder B-fragments
    const _Float16* __restrict__ SdSw,      // state-decoder B-fragments
    const float* __restrict__ bias,
    const float* __restrict__ gain,
    const float* __restrict__ dec,          // [NN][DOUT]
    unsigned long long* __restrict__ psq,   // [2][BTILES][NTILES][BT][DS] tagged
    float* __restrict__ out)
{
    __shared__ _Float16 xh[16][136];  // x_aug f16 (A-operand), rows 8..15 zero
    __shared__ _Float16 Ash[16][520]; // activations f16 (A-operand for decode)
    __shared__ float Dp[4][8][17];    // decode kh-pair partials

    const int tid = threadIdx.x;
    const int nt = blockIdx.x & (NTILES - 1);
    const int bt = blockIdx.x >> 2;
    const int n0 = nt * NT;
    const int b0 = bt * BT;

    const int w = tid >> 6;            // wave 0..7
    const int l = tid & 63;
    const int rs = tid >> 6;           // fan-in row 0..7
    const int cs = tid & 63;           // fan-in col
    const int m16 = l & 15;            // fragment row/col index
    const int q8  = (l >> 4) << 3;     // fragment k sub-offset
    const int cg  = w & 3;             // decode col group
    const int kh  = w >> 2;            // decode neuron half

    const _Float16* EtW = EtSw + ((size_t)(nt * 8 + w) << 13);
    const _Float16* SdW = SdSw + ((size_t)((nt * 4 + cg) * 2 + kh) << 12);

    // ---- register-resident weight fragments (loaded once) ----
    half8 etf[4][4];   // [ntile][ktile]
    #pragma unroll
    for (int n4 = 0; n4 < 4; ++n4)
        #pragma unroll
        for (int kt = 0; kt < 4; ++kt)
            etf[n4][kt] = *(const half8*)&EtW[(n4 << 11) + (kt << 9) + (size_t)l * 8];
    half8 sdf[8];
    #pragma unroll
    for (int kt = 0; kt < 8; ++kt)
        sdf[kt] = *(const half8*)&SdW[(kt << 9) + (size_t)l * 8];

    // epilogue params
    float gv[4], bv[4];
    #pragma unroll
    for (int n4 = 0; n4 < 4; ++n4) {
        gv[n4] = gain[n0 + w * 64 + n4 * 16 + m16];
        bv[n4] = bias[n0 + w * 64 + n4 * 16 + m16];
    }

    // fan-in base: this thread's 4 partials (p = 0..3), stride BT*DS u64s
    const size_t fan_base = ((size_t)bt * NTILES) * BT * DS + (size_t)rs * DS + cs;

    // zero xh once (rows 8..15 stay zero; rows 0..7 rewritten per step)
    {
        unsigned int* xz = (unsigned int*)&xh[0][0];
        for (int i2 = tid; i2 < 16 * 136 / 2; i2 += THREADS) xz[i2] = 0u;
    }
    __syncthreads();

    for (int t = 0; t < T_; ++t) {
        // ---- stage u_t into xh rows 0..7, k 0..63 ----
        if (tid < 128) {
            const int r = tid >> 4, c = (tid & 15) << 2;
            const float4 uv = *(const float4*)&seq[((size_t)(b0 + r) * T_ + t) * DIN + c];
            _Float16* p = &xh[r][c];
            p[0] = (_Float16)uv.x; p[1] = (_Float16)uv.y;
            p[2] = (_Float16)uv.z; p[3] = (_Float16)uv.w;
        }
        __syncthreads();   // B0: u_t staged

        // ---- encode phase A: k-tiles 0,1 (cols 0..63 only) ----
        f32x4 acc[4];
        #pragma unroll
        for (int n4 = 0; n4 < 4; ++n4) acc[n4] = (f32x4){0.f, 0.f, 0.f, 0.f};
        {
            const half8 af0 = *(const half8*)&xh[m16][q8];
            const half8 af1 = *(const half8*)&xh[m16][32 + q8];
            #pragma unroll
            for (int n4 = 0; n4 < 4; ++n4) {
                acc[n4] = __builtin_amdgcn_mfma_f32_16x16x32_f16(af0, etf[n4][0], acc[n4], 0, 0, 0);
                acc[n4] = __builtin_amdgcn_mfma_f32_16x16x32_f16(af1, etf[n4][1], acc[n4], 0, 0, 0);
            }
        }

        // ---- acquire s(t-1): per-thread tag-poll on own 4 packed partials ----
        if (t > 0) {
            const unsigned long long* pb = psq + (size_t)((t - 1) & 1) * PSQ_ELEMS + fan_base;
            const unsigned utag = (unsigned)t;
            unsigned long long v0, v1, v2, v3;
            for (;;) {
                v0 = __hip_atomic_load(pb + 0 * (BT * DS), __ATOMIC_RELAXED, __HIP_MEMORY_SCOPE_AGENT);
                v1 = __hip_atomic_load(pb + 1 * (BT * DS), __ATOMIC_RELAXED, __HIP_MEMORY_SCOPE_AGENT);
                v2 = __hip_atomic_load(pb + 2 * (BT * DS), __ATOMIC_RELAXED, __HIP_MEMORY_SCOPE_AGENT);
                v3 = __hip_atomic_load(pb + 3 * (BT * DS), __ATOMIC_RELAXED, __HIP_MEMORY_SCOPE_AGENT);
                if ((unsigned)(v0 >> 32) == utag && (unsigned)(v1 >> 32) == utag &&
                    (unsigned)(v2 >> 32) == utag && (unsigned)(v3 >> 32) == utag)
                    break;
            }
            const float ssum = __uint_as_float((unsigned)v0) + __uint_as_float((unsigned)v1)
                             + __uint_as_float((unsigned)v2) + __uint_as_float((unsigned)v3);
            xh[rs][DIN + cs] = (_Float16)ssum;
        } else {
            xh[rs][DIN + cs] = (_Float16)0.f;
        }
        __syncthreads();   // B1: state half ready

        // ---- encode phase B: k-tiles 2,3 ----
        {
            const half8 af2 = *(const half8*)&xh[m16][64 + q8];
            const half8 af3 = *(const half8*)&xh[m16][96 + q8];
            #pragma unroll
            for (int n4 = 0; n4 < 4; ++n4) {
                acc[n4] = __builtin_amdgcn_mfma_f32_16x16x32_f16(af2, etf[n4][2], acc[n4], 0, 0, 0);
                acc[n4] = __builtin_amdgcn_mfma_f32_16x16x32_f16(af3, etf[n4][3], acc[n4], 0, 0, 0);
            }
        }

        // ---- epilogue: rows 0..7 live in lanes 0..31 (row=(l>>4)*4+reg) ----
        if (l < 32) {
            const int rq = (l >> 4) << 2;
            #pragma unroll
            for (int n4 = 0; n4 < 4; ++n4) {
                const int n = w * 64 + n4 * 16 + m16;
                Ash[rq + 0][n] = (_Float16)fabsf(gv[n4] * acc[n4][0] + bv[n4]);
                Ash[rq + 1][n] = (_Float16)fabsf(gv[n4] * acc[n4][1] + bv[n4]);
                Ash[rq + 2][n] = (_Float16)fabsf(gv[n4] * acc[n4][2] + bv[n4]);
                Ash[rq + 3][n] = (_Float16)fabsf(gv[n4] * acc[n4][3] + bv[n4]);
            }
        }
        __syncthreads();   // B2: activations ready

        if (t == T_ - 1) {
            // ---- final projection: out += A_tile @ dec_tile ----
            for (int idx = tid; idx < BT * DOUT; idx += THREADS) {
                const int r = idx / DOUT;
                const int d = idx % DOUT;
                float o = 0.f;
                #pragma unroll 8
                for (int n = 0; n < NT; ++n)
                    o += (float)Ash[r][n] * dec[(size_t)(n0 + n) * DOUT + d];
                atomicAdd(&out[(size_t)(b0 + r) * DOUT + d], o);
            }
            return;
        }

        // ---- decode on MFMA: wave (cg,kh) -> cols [16cg,+16), neurons [256kh,+256) ----
        {
            f32x4 d0 = (f32x4){0.f, 0.f, 0.f, 0.f};
            f32x4 d1 = (f32x4){0.f, 0.f, 0.f, 0.f};
            #pragma unroll
            for (int kt = 0; kt < 8; kt += 2) {
                const half8 a0 = *(const half8*)&Ash[m16][kh * 256 + kt * 32 + q8];
                d0 = __builtin_amdgcn_mfma_f32_16x16x32_f16(a0, sdf[kt], d0, 0, 0, 0);
                const half8 a1 = *(const half8*)&Ash[m16][kh * 256 + (kt + 1) * 32 + q8];
                d1 = __builtin_amdgcn_mfma_f32_16x16x32_f16(a1, sdf[kt + 1], d1, 0, 0, 0);
            }
            d0[0] += d1[0]; d0[1] += d1[1]; d0[2] += d1[2]; d0[3] += d1[3];

            if (kh == 1 && l < 32) {
                const int rq = (l >> 4) << 2;
                Dp[cg][rq + 0][m16] = d0[0];
                Dp[cg][rq + 1][m16] = d0[1];
                Dp[cg][rq + 2][m16] = d0[2];
                Dp[cg][rq + 3][m16] = d0[3];
            }
            __syncthreads();   // B3: Dp ready

            if (kh == 0 && l < 32) {
                const int rq = (l >> 4) << 2;
                unsigned long long* pw = psq + (size_t)(t & 1) * PSQ_ELEMS
                    + (((size_t)bt * NTILES + nt) * BT) * DS + 16 * cg + m16;
                const unsigned long long tg = (unsigned long long)(unsigned)(t + 1) << 32;
                #pragma unroll
                for (int r = 0; r < 4; ++r) {
                    const float v = d0[r] + Dp[cg][rq + r][m16];
                    __hip_atomic_store(pw + (size_t)(rq + r) * DS,
                                       tg | (unsigned long long)__float_as_uint(v),
                                       __ATOMIC_RELAXED, __HIP_MEMORY_SCOPE_AGENT);
                }
            }
            // no drain, no counter, no arrive barrier — tag rides with the data
        }
    }
}

extern "C" void kernel_launch(void* const* d_in, const int* in_sizes, int n_in,
                              void* d_out, int out_size, void* d_ws, size_t ws_size,
                              hipStream_t stream) {
    const float* seq  = (const float*)d_in[0];
    const float* enc  = (const float*)d_in[1];
    const float* bias = (const float*)d_in[2];
    const float* gain = (const float*)d_in[3];
    const float* sd   = (const float*)d_in[4];
    const float* dec  = (const float*)d_in[5];
    float* out = (float*)d_out;
    float* ws  = (float*)d_ws;   // psq[2] (2 MB) | EtSw | SdSw  (~2.8 MB)

    pre_kernel<<<dim3(1024), dim3(256), 0, stream>>>(enc, sd, ws, out);

    unsigned long long* psq = (unsigned long long*)ws;
    const _Float16* EtSw = (const _Float16*)(ws + ETSW_OFF);
    const _Float16* SdSw = (const _Float16*)(ws + SDSW_OFF);

    persist_kernel<<<dim3(NWG), dim3(THREADS), 0, stream>>>(
        seq, EtSw, SdSw, bias, gain, dec, psq, out);
}

// Round 18
// 608.947 us; speedup vs baseline: 1.3911x; 1.0525x over previous
//
#include <hip/hip_runtime.h>
#include <math.h>

// Problem constants
#define B_    512
#define T_    256
#define DIN   64
#define DS    64
#define KK    128   // DIN + DS
#define NN    2048
#define DOUT  10

// Tiling: 256 WGs = NTILES(4) x BTILES(64), 512 thr (8 waves), 1 WG/CU.
#define NT      512
#define BT      8
#define NTILES  (NN / NT)      // 4
#define BTILES  (B_ / BT)      // 64
#define THREADS 512
#define NWG     (NTILES * BTILES)   // 256

// Workspace: psq (u64 tagged partials, double-buffered) | EtSw | SdSw
#define PSQ_ELEMS  ((size_t)BTILES * NTILES * BT * DS)  // 131072 u64 per buffer
#define PS_FLOATS  (4 * PSQ_ELEMS)                      // 2 buffers as float count
#define ETSW_OFF   PS_FLOATS
#define ETSW_F16   ((size_t)KK * NN)                    // 262144 f16 = 512 KB
#define SDSW_OFF   (ETSW_OFF + ETSW_F16 / 2)
#define SDSW_F16   ((size_t)NN * DS)                    // 131072 f16 = 256 KB

typedef _Float16 half8 __attribute__((ext_vector_type(8)));
typedef float    f32x4 __attribute__((ext_vector_type(4)));

__global__ __launch_bounds__(256) void pre_kernel(const float* __restrict__ enc,
                                                  const float* __restrict__ sd,
                                                  float* __restrict__ ws,
                                                  float* __restrict__ out) {
    size_t i = (size_t)blockIdx.x * blockDim.x + threadIdx.x;
    size_t stride = (size_t)gridDim.x * blockDim.x;
    // zero tagged-partial buffers (tag 0 never matches: consumer tags >= 1)
    unsigned long long* psq = (unsigned long long*)ws;
    for (size_t x = i; x < 2 * PSQ_ELEMS; x += stride) psq[x] = 0ull;
    // EtSw: B-fragments, 8-wave ownership (R13-verified).
    _Float16* EtSw = (_Float16*)(ws + ETSW_OFF);
    for (size_t x = i; x < (size_t)KK * NN; x += stride) {
        const int j     = (int)(x & 7);
        const int lane  = (int)((x >> 3) & 63);
        const int ktile = (int)((x >> 9) & 3);
        const int ntile = (int)((x >> 11) & 3);
        const int w     = (int)((x >> 13) & 7);
        const int nt    = (int)(x >> 16);
        const int n = nt * 512 + w * 64 + ntile * 16 + (lane & 15);
        const int k = ktile * 32 + ((lane >> 4) << 3) + j;
        EtSw[x] = (_Float16)enc[(size_t)n * KK + k];
    }
    // SdSw: decode B-fragments, FULL-K ownership (R12-verified layout):
    // per (nt,cg): 16 ktiles x 64 lanes x 8. n = nt*512 + ktile*32 + (lane>>4)*8 + j,
    // c = cg*16 + (lane&15).
    _Float16* SdSw = (_Float16*)(ws + SDSW_OFF);
    for (size_t x = i; x < (size_t)NN * DS; x += stride) {
        const int j     = (int)(x & 7);
        const int lane  = (int)((x >> 3) & 63);
        const int ktile = (int)((x >> 9) & 15);
        const int cg    = (int)((x >> 13) & 3);
        const int nt    = (int)(x >> 15);
        const int n = nt * 512 + ktile * 32 + ((lane >> 4) << 3) + j;
        const int c = cg * 16 + (lane & 15);
        SdSw[x] = (_Float16)sd[(size_t)n * DS + c];
    }
    for (size_t x = i; x < (size_t)B_ * DOUT; x += stride) out[x] = 0.0f;
}

// R17 core (tagged-payload exchange, best: 589 us steady) with 3 chain cuts:
//  1. full-K decode on waves 0-3 (16 MFMA, R12 shape) — Dp reduce deleted.
//  2. waves 4-7 stage u_{t+1} during decode — loop-top barrier deleted (3/step).
//  3. speculative poll: tagged loads ISSUED before encode-A, tag check after —
//     one load RTT hidden behind compute; retry only on stale tags.
// launch_bounds(512,1): sdf[16] needs ~170 VGPR; (512,2) would cap at 128
// and spill (R9 lesson). Grid = 256 = CU count -> 1 WG/CU regardless.
// Safety: R17 tag induction rests on true data dependency (fan-in -> Ash ->
// decode stores) — holds fully relaxed; staging waves touch only LDS.
__global__ __launch_bounds__(THREADS, 1) void persist_kernel(
    const float* __restrict__ seq,          // [B][T][DIN]
    const _Float16* __restrict__ EtSw,      // encoder B-fragments
    const _Float16* __restrict__ SdSw,      // state-decoder B-fragments
    const float* __restrict__ bias,
    const float* __restrict__ gain,
    const float* __restrict__ dec,          // [NN][DOUT]
    unsigned long long* __restrict__ psq,   // [2][BTILES][NTILES][BT][DS] tagged
    float* __restrict__ out)
{
    __shared__ _Float16 xh[16][136];  // x_aug f16 (A-operand), rows 8..15 zero
    __shared__ _Float16 Ash[16][520]; // activations f16 (A-operand for decode)

    const int tid = threadIdx.x;
    const int nt = blockIdx.x & (NTILES - 1);
    const int bt = blockIdx.x >> 2;
    const int n0 = nt * NT;
    const int b0 = bt * BT;

    const int w = tid >> 6;            // wave 0..7
    const int l = tid & 63;
    const int rs = tid >> 6;           // fan-in row 0..7
    const int cs = tid & 63;           // fan-in col
    const int m16 = l & 15;            // fragment row/col index
    const int q8  = (l >> 4) << 3;     // fragment k sub-offset

    const _Float16* EtW = EtSw + ((size_t)(nt * 8 + w) << 13);
    const _Float16* SdW = SdSw + ((size_t)(nt * 4 + (w & 3)) << 13);

    // ---- register-resident weight fragments (loaded once) ----
    half8 etf[4][4];   // [ntile][ktile]
    #pragma unroll
    for (int n4 = 0; n4 < 4; ++n4)
        #pragma unroll
        for (int kt = 0; kt < 4; ++kt)
            etf[n4][kt] = *(const half8*)&EtW[(n4 << 11) + (kt << 9) + (size_t)l * 8];
    half8 sdf[16];     // full-K decode fragments (used by waves 0..3)
    #pragma unroll
    for (int kt = 0; kt < 16; ++kt)
        sdf[kt] = *(const half8*)&SdW[(kt << 9) + (size_t)l * 8];

    // epilogue params
    float gv[4], bv[4];
    #pragma unroll
    for (int n4 = 0; n4 < 4; ++n4) {
        gv[n4] = gain[n0 + w * 64 + n4 * 16 + m16];
        bv[n4] = bias[n0 + w * 64 + n4 * 16 + m16];
    }

    // fan-in base: this thread's 4 partials (p = 0..3), stride BT*DS u64s
    const size_t fan_base = ((size_t)bt * NTILES) * BT * DS + (size_t)rs * DS + cs;

    // preamble: zero xh (rows 8..15 stay zero), stage u_0
    {
        unsigned int* xz = (unsigned int*)&xh[0][0];
        for (int i2 = tid; i2 < 16 * 136 / 2; i2 += THREADS) xz[i2] = 0u;
    }
    __syncthreads();
    if (tid < 128) {
        const int r = tid >> 4, c = (tid & 15) << 2;
        const float4 uv = *(const float4*)&seq[((size_t)(b0 + r) * T_ + 0) * DIN + c];
        _Float16* p = &xh[r][c];
        p[0] = (_Float16)uv.x; p[1] = (_Float16)uv.y;
        p[2] = (_Float16)uv.z; p[3] = (_Float16)uv.w;
    }
    __syncthreads();

    for (int t = 0; t < T_; ++t) {
        // ---- speculative poll issue: loads in flight during encode-A ----
        const unsigned long long* pb =
            psq + (size_t)((t - 1) & 1) * PSQ_ELEMS + fan_base;
        unsigned long long v0 = 0, v1 = 0, v2 = 0, v3 = 0;
        if (t > 0) {
            v0 = __hip_atomic_load(pb + 0 * (BT * DS), __ATOMIC_RELAXED, __HIP_MEMORY_SCOPE_AGENT);
            v1 = __hip_atomic_load(pb + 1 * (BT * DS), __ATOMIC_RELAXED, __HIP_MEMORY_SCOPE_AGENT);
            v2 = __hip_atomic_load(pb + 2 * (BT * DS), __ATOMIC_RELAXED, __HIP_MEMORY_SCOPE_AGENT);
            v3 = __hip_atomic_load(pb + 3 * (BT * DS), __ATOMIC_RELAXED, __HIP_MEMORY_SCOPE_AGENT);
        }

        // ---- encode phase A: k-tiles 0,1 (u_t staged last step; no barrier) ----
        f32x4 acc[4];
        #pragma unroll
        for (int n4 = 0; n4 < 4; ++n4) acc[n4] = (f32x4){0.f, 0.f, 0.f, 0.f};
        {
            const half8 af0 = *(const half8*)&xh[m16][q8];
            const half8 af1 = *(const half8*)&xh[m16][32 + q8];
            #pragma unroll
            for (int n4 = 0; n4 < 4; ++n4) {
                acc[n4] = __builtin_amdgcn_mfma_f32_16x16x32_f16(af0, etf[n4][0], acc[n4], 0, 0, 0);
                acc[n4] = __builtin_amdgcn_mfma_f32_16x16x32_f16(af1, etf[n4][1], acc[n4], 0, 0, 0);
            }
        }

        // ---- acquire s(t-1): check speculative values, retry on stale tags ----
        if (t > 0) {
            const unsigned utag = (unsigned)t;
            for (;;) {
                if ((unsigned)(v0 >> 32) == utag && (unsigned)(v1 >> 32) == utag &&
                    (unsigned)(v2 >> 32) == utag && (unsigned)(v3 >> 32) == utag)
                    break;
                v0 = __hip_atomic_load(pb + 0 * (BT * DS), __ATOMIC_RELAXED, __HIP_MEMORY_SCOPE_AGENT);
                v1 = __hip_atomic_load(pb + 1 * (BT * DS), __ATOMIC_RELAXED, __HIP_MEMORY_SCOPE_AGENT);
                v2 = __hip_atomic_load(pb + 2 * (BT * DS), __ATOMIC_RELAXED, __HIP_MEMORY_SCOPE_AGENT);
                v3 = __hip_atomic_load(pb + 3 * (BT * DS), __ATOMIC_RELAXED, __HIP_MEMORY_SCOPE_AGENT);
            }
            const float ssum = __uint_as_float((unsigned)v0) + __uint_as_float((unsigned)v1)
                             + __uint_as_float((unsigned)v2) + __uint_as_float((unsigned)v3);
            xh[rs][DIN + cs] = (_Float16)ssum;
        } else {
            xh[rs][DIN + cs] = (_Float16)0.f;
        }
        __syncthreads();   // B1: state half ready

        // ---- encode phase B: k-tiles 2,3 ----
        {
            const half8 af2 = *(const half8*)&xh[m16][64 + q8];
            const half8 af3 = *(const half8*)&xh[m16][96 + q8];
            #pragma unroll
            for (int n4 = 0; n4 < 4; ++n4) {
                acc[n4] = __builtin_amdgcn_mfma_f32_16x16x32_f16(af2, etf[n4][2], acc[n4], 0, 0, 0);
                acc[n4] = __builtin_amdgcn_mfma_f32_16x16x32_f16(af3, etf[n4][3], acc[n4], 0, 0, 0);
            }
        }

        // ---- epilogue: rows 0..7 live in lanes 0..31 (row=(l>>4)*4+reg) ----
        if (l < 32) {
            const int rq = (l >> 4) << 2;
            #pragma unroll
            for (int n4 = 0; n4 < 4; ++n4) {
                const int n = w * 64 + n4 * 16 + m16;
                Ash[rq + 0][n] = (_Float16)fabsf(gv[n4] * acc[n4][0] + bv[n4]);
                Ash[rq + 1][n] = (_Float16)fabsf(gv[n4] * acc[n4][1] + bv[n4]);
                Ash[rq + 2][n] = (_Float16)fabsf(gv[n4] * acc[n4][2] + bv[n4]);
                Ash[rq + 3][n] = (_Float16)fabsf(gv[n4] * acc[n4][3] + bv[n4]);
            }
        }
        __syncthreads();   // B2: activations ready

        if (t == T_ - 1) {
            // ---- final projection: out += A_tile @ dec_tile ----
            for (int idx = tid; idx < BT * DOUT; idx += THREADS) {
                const int r = idx / DOUT;
                const int d = idx % DOUT;
                float o = 0.f;
                #pragma unroll 8
                for (int n = 0; n < NT; ++n)
                    o += (float)Ash[r][n] * dec[(size_t)(n0 + n) * DOUT + d];
                atomicAdd(&out[(size_t)(b0 + r) * DOUT + d], o);
            }
            return;
        }

        // ---- decode (waves 0-3, full K=512) + u_{t+1} staging (waves 4-7) ----
        if (w < 4) {
            f32x4 d0 = (f32x4){0.f, 0.f, 0.f, 0.f};
            f32x4 d1 = (f32x4){0.f, 0.f, 0.f, 0.f};
            #pragma unroll
            for (int kt = 0; kt < 16; kt += 2) {
                const half8 a0 = *(const half8*)&Ash[m16][kt * 32 + q8];
                d0 = __builtin_amdgcn_mfma_f32_16x16x32_f16(a0, sdf[kt], d0, 0, 0, 0);
                const half8 a1 = *(const half8*)&Ash[m16][(kt + 1) * 32 + q8];
                d1 = __builtin_amdgcn_mfma_f32_16x16x32_f16(a1, sdf[kt + 1], d1, 0, 0, 0);
            }
            d0[0] += d1[0]; d0[1] += d1[1]; d0[2] += d1[2]; d0[3] += d1[3];
            // C/D: col = lane&15 -> state col 16w+m16; rows 0..7 in lanes 0..31
            if (l < 32) {
                const int rq = (l >> 4) << 2;
                unsigned long long* pw = psq + (size_t)(t & 1) * PSQ_ELEMS
                    + (((size_t)bt * NTILES + nt) * BT) * DS + 16 * w + m16;
                const unsigned long long tg = (unsigned long long)(unsigned)(t + 1) << 32;
                #pragma unroll
                for (int r = 0; r < 4; ++r) {
                    const float v = d0[rq >= 4 ? r : r] + 0.f;  // keep index simple
                    const float vv = d0[r];
                    (void)v;
                    __hip_atomic_store(pw + (size_t)(rq + r) * DS,
                                       tg | (unsigned long long)__float_as_uint(vv),
                                       __ATOMIC_RELAXED, __HIP_MEMORY_SCOPE_AGENT);
                }
            }
        } else if (l < 32) {
            // stage u_{t+1}: 4 waves x 32 lanes = 128 float4 loads
            const int idx = ((w - 4) << 5) + l;     // 0..127
            const int r = idx >> 4, c = (idx & 15) << 2;
            const float4 uv =
                *(const float4*)&seq[((size_t)(b0 + r) * T_ + (t + 1)) * DIN + c];
            _Float16* p = &xh[r][c];
            p[0] = (_Float16)uv.x; p[1] = (_Float16)uv.y;
            p[2] = (_Float16)uv.z; p[3] = (_Float16)uv.w;
        }
        __syncthreads();   // B3: decode reads of Ash done + u_{t+1} staged
        // no drain, no counter — tag rides with the data
    }
}

extern "C" void kernel_launch(void* const* d_in, const int* in_sizes, int n_in,
                              void* d_out, int out_size, void* d_ws, size_t ws_size,
                              hipStream_t stream) {
    const float* seq  = (const float*)d_in[0];
    const float* enc  = (const float*)d_in[1];
    const float* bias = (const float*)d_in[2];
    const float* gain = (const float*)d_in[3];
    const float* sd   = (const float*)d_in[4];
    const float* dec  = (const float*)d_in[5];
    float* out = (float*)d_out;
    float* ws  = (float*)d_ws;   // psq[2] (2 MB) | EtSw | SdSw  (~2.8 MB)

    pre_kernel<<<dim3(1024), dim3(256), 0, stream>>>(enc, sd, ws, out);

    unsigned long long* psq = (unsigned long long*)ws;
    const _Float16* EtSw = (const _Float16*)(ws + ETSW_OFF);
    const _Float16* SdSw = (const _Float16*)(ws + SDSW_OFF);

    persist_kernel<<<dim3(NWG), dim3(THREADS), 0, stream>>>(
        seq, EtSw, SdSw, bias, gain, dec, psq, out);
}